// Round 5
// baseline (377.864 us; speedup 1.0000x reference)
//
#include <hip/hip_runtime.h>
#include <cstdint>
#include <cstddef>

// MI355X self-attention: B=4 S=2048 E=1024 H=16 D=64
// R12: (1) GEMMs reverted to R7 exact (best measured: 111+38 µs; four
//  alternative schedules R8/R9/R10 all 114-122 µs — per-block staging
//  throughput is invariant ~5.5 B/cy across ALL schedules incl. m97 ref).
//  (2) attn experiment: qg 2->4 (64 q rows/wave, 256/block, grid 512).
//  Doubles per-wave ILP chains AND halves K/V staging per output — wins
//  under both the latency-chain and staging-wall theories.

typedef __attribute__((ext_vector_type(8))) short short8;   // 8 x bf16
typedef __attribute__((ext_vector_type(4))) float float4_;
typedef unsigned int u32;
typedef unsigned short u16;

__device__ __forceinline__ u16 f2b(float f) {
  u32 u = __float_as_uint(f);
  u += 0x7FFFu + ((u >> 16) & 1u);   // RNE
  return (u16)(u >> 16);
}

__device__ __forceinline__ float fexp2(float x) {
#if __has_builtin(__builtin_amdgcn_exp2f)
  return __builtin_amdgcn_exp2f(x);   // bare v_exp_f32
#else
  return exp2f(x);
#endif
}

// pack (lo,hi) floats -> bf16x2 by truncation (1 v_perm)
__device__ __forceinline__ u32 pk_trunc(float lo, float hi) {
#if __has_builtin(__builtin_amdgcn_perm)
  return __builtin_amdgcn_perm(__float_as_uint(hi), __float_as_uint(lo), 0x07060302);
#else
  return (__float_as_uint(hi) & 0xFFFF0000u) | (__float_as_uint(lo) >> 16);
#endif
}

#if __has_builtin(__builtin_amdgcn_fdot2_f32_bf16)
typedef __bf16 bf16x2 __attribute__((ext_vector_type(2)));
__device__ __forceinline__ float accum_pk(u32 pk, float acc) {
  bf16x2 p = __builtin_bit_cast(bf16x2, pk);
  bf16x2 one = __builtin_bit_cast(bf16x2, (u32)0x3F803F80u);
  return __builtin_amdgcn_fdot2_f32_bf16(p, one, acc, false);
}
#else
__device__ __forceinline__ float accum_pk(u32 pk, float acc) {
  return acc + __uint_as_float(pk << 16) + __uint_as_float(pk & 0xFFFF0000u);
}
#endif

// async global->LDS, 16B per lane; LDS dst must be wave-uniform base + lane*16
__device__ __forceinline__ void async_cp16(const void* g, void* l) {
  __builtin_amdgcn_global_load_lds(
      (const __attribute__((address_space(1))) u32*)g,
      (__attribute__((address_space(3))) u32*)l, 16, 0, 0);
}

// ---------------- fused pre-pass ----------------
// blocks [0,8192): cvt x->bf16; [8192,11264): transpose w_qkv; rest: w_out.

__device__ __forceinline__ void transpose_block(const float* __restrict__ in,
                                                u16* __restrict__ out,
                                                int R, int C, int bx, int by,
                                                float t[32][33]) {
  int tx = threadIdx.x & 31, ty = threadIdx.x >> 5;
  int r0 = by * 32, c0 = bx * 32;
#pragma unroll
  for (int k = 0; k < 4; k++)
    t[ty + 8 * k][tx] = in[(size_t)(r0 + ty + 8 * k) * C + c0 + tx];
  __syncthreads();
#pragma unroll
  for (int k = 0; k < 4; k++)
    out[(size_t)(c0 + ty + 8 * k) * R + r0 + tx] = f2b(t[tx][ty + 8 * k]);
}

__global__ void prepass_kernel(const float* __restrict__ x, u16* __restrict__ Xb,
                               const float* __restrict__ wqkv, u16* __restrict__ Wqt,
                               const float* __restrict__ wout, u16* __restrict__ Wot) {
  __shared__ float t[32][33];
  int gid = blockIdx.x;
  if (gid < 8192) {
    int i = gid * 256 + threadIdx.x;
    float4 v = ((const float4*)x)[i];
    uint2 p;
    p.x = (u32)f2b(v.x) | ((u32)f2b(v.y) << 16);
    p.y = (u32)f2b(v.z) | ((u32)f2b(v.w) << 16);
    ((uint2*)Xb)[i] = p;
  } else if (gid < 11264) {
    int j = gid - 8192;
    transpose_block(wqkv, Wqt, 1024, 3072, j % 96, j / 96, t);
  } else {
    int j = gid - 11264;
    transpose_block(wout, Wot, 1024, 1024, j % 32, j / 32, t);
  }
}

// V[bh][s][d] bf16 -> Vt[bh][d][s] bf16. 64x64 tiles. grid (32, 64), block 256.
__global__ void transpose_v(const u16* __restrict__ V, u16* __restrict__ Vt) {
  __shared__ u16 t[64][80];
  int bh = blockIdx.y, s0 = blockIdx.x * 64;
  const u16* Vh = V + (size_t)bh * 2048 * 64;
  u16* Vth = Vt + (size_t)bh * 64 * 2048;
  int tr = threadIdx.x >> 3;            // 0..31
  int tc = (threadIdx.x & 7) * 8;       // 0..56 step 8
#pragma unroll
  for (int p = 0; p < 2; p++) {
    int r = p * 32 + tr;
    *(uint4*)&t[r][tc] = *(const uint4*)(Vh + (size_t)(s0 + r) * 64 + tc);
  }
  __syncthreads();
#pragma unroll
  for (int p = 0; p < 2; p++) {
    int d = p * 32 + tr;
    u16 tmp[8];
#pragma unroll
    for (int k = 0; k < 8; k++) tmp[k] = t[tc + k][d];
    *(uint4*)(Vth + (size_t)d * 2048 + s0 + tc) = *(uint4*)tmp;
  }
}

// ---------------- GEMM kernels (R7 exact: 128x128 tile, 16x16x32 bf16 MFMA) -------

__global__ __launch_bounds__(256) void gemm_qkv_kernel(
    const u16* __restrict__ A, const u16* __restrict__ Bt,
    u16* __restrict__ QKV) {   // QKV = 3 x 16MB consecutive [b,h,s,d] buffers
  const int K = 1024;
  __shared__ short8 lA[2][512];   // 16 KB
  __shared__ short8 lB[2][512];   // 16 KB
  int tid = threadIdx.x;
  int w = tid >> 6, l = tid & 63, lr = l & 15, lq = l >> 4;
  int gid = blockIdx.x;
  int xcd = gid & 7, j = gid >> 3;     // 192 blocks per XCD
  int yloc = j & 7, xt = j >> 3;       // y-minor: 8 y per xt before next B-tile
  int m0 = (xcd * 8 + yloc) * 128, n0 = xt * 128;
  int wm = w & 1, wn = w >> 1;
  float4_ acc[4][4] = {};

  const u16* gA0 = A + (size_t)(m0 + w * 32 + lr) * K + lq * 8;
  const u16* gA1 = gA0 + 16 * K;
  const u16* gB0 = Bt + (size_t)(n0 + w * 32 + lr) * K + lq * 8;
  const u16* gB1 = gB0 + 16 * K;

  auto stage = [&](int buf, int k0) {
    async_cp16(gA0 + k0, &lA[buf][(w * 2 + 0) * 64 + l]);
    async_cp16(gA1 + k0, &lA[buf][(w * 2 + 1) * 64 + l]);
    async_cp16(gB0 + k0, &lB[buf][(w * 2 + 0) * 64 + l]);
    async_cp16(gB1 + k0, &lB[buf][(w * 2 + 1) * 64 + l]);
  };
  auto compute = [&](int buf) {
    short8 af[4], bf[4];
#pragma unroll
    for (int t = 0; t < 4; t++) {
      af[t] = lA[buf][(wm * 4 + t) * 64 + l];
      bf[t] = lB[buf][(wn * 4 + t) * 64 + l];
    }
#pragma unroll
    for (int mt = 0; mt < 4; mt++)
#pragma unroll
      for (int nt = 0; nt < 4; nt++)
        acc[mt][nt] = __builtin_amdgcn_mfma_f32_16x16x32_bf16(af[mt], bf[nt], acc[mt][nt], 0, 0, 0);
  };

  stage(0, 0);
  for (int k0 = 0; k0 < K; k0 += 64) {
    __syncthreads();
    stage(1, k0 + 32);
    compute(0);
    __syncthreads();
    if (k0 + 64 < K) stage(0, k0 + 64);
    compute(1);
  }

  const float qsc = 0.18033688011112042f;  // d^-0.5 * log2(e)
#pragma unroll
  for (int nt = 0; nt < 4; nt++) {
    int gn = n0 + wn * 64 + nt * 16 + lr;
    int sel = gn >> 10;
    int h = (gn >> 6) & 15;
    int d = gn & 63;
    float sc = (sel == 0) ? qsc : 1.0f;
    u16* dst = QKV + (size_t)sel * 8388608 + ((size_t)h * 2048) * 64 + d;
#pragma unroll
    for (int mt = 0; mt < 4; mt++) {
#pragma unroll
      for (int r = 0; r < 4; r++) {
        int gm = m0 + wm * 64 + mt * 16 + lq * 4 + r;
        int b = gm >> 11, s = gm & 2047;
        dst[((size_t)b * 16 * 2048 + s) * 64] = f2b(acc[mt][nt][r] * sc);
      }
    }
  }
}

__global__ __launch_bounds__(256) void gemm_out_kernel(
    const u16* __restrict__ A, const u16* __restrict__ Bt,
    const float* __restrict__ bias, float* __restrict__ out) {
  const int K = 1024;
  __shared__ short8 lA[2][512];
  __shared__ short8 lB[2][512];
  int tid = threadIdx.x;
  int w = tid >> 6, l = tid & 63, lr = l & 15, lq = l >> 4;
  int gid = blockIdx.x;
  int xcd = gid & 7, j = gid >> 3;     // 64 blocks per XCD
  int yloc = j & 7, xt = j >> 3;       // 8 y x 8 x per XCD
  int m0 = (xcd * 8 + yloc) * 128, n0 = xt * 128;
  int wm = w & 1, wn = w >> 1;
  float4_ acc[4][4] = {};

  const u16* gA0 = A + (size_t)(m0 + w * 32 + lr) * K + lq * 8;
  const u16* gA1 = gA0 + 16 * K;
  const u16* gB0 = Bt + (size_t)(n0 + w * 32 + lr) * K + lq * 8;
  const u16* gB1 = gB0 + 16 * K;

  auto stage = [&](int buf, int k0) {
    async_cp16(gA0 + k0, &lA[buf][(w * 2 + 0) * 64 + l]);
    async_cp16(gA1 + k0, &lA[buf][(w * 2 + 1) * 64 + l]);
    async_cp16(gB0 + k0, &lB[buf][(w * 2 + 0) * 64 + l]);
    async_cp16(gB1 + k0, &lB[buf][(w * 2 + 1) * 64 + l]);
  };
  auto compute = [&](int buf) {
    short8 af[4], bf[4];
#pragma unroll
    for (int t = 0; t < 4; t++) {
      af[t] = lA[buf][(wm * 4 + t) * 64 + l];
      bf[t] = lB[buf][(wn * 4 + t) * 64 + l];
    }
#pragma unroll
    for (int mt = 0; mt < 4; mt++)
#pragma unroll
      for (int nt = 0; nt < 4; nt++)
        acc[mt][nt] = __builtin_amdgcn_mfma_f32_16x16x32_bf16(af[mt], bf[nt], acc[mt][nt], 0, 0, 0);
  };

  stage(0, 0);
  for (int k0 = 0; k0 < K; k0 += 64) {
    __syncthreads();
    stage(1, k0 + 32);
    compute(0);
    __syncthreads();
    if (k0 + 64 < K) stage(0, k0 + 64);
    compute(1);
  }

#pragma unroll
  for (int nt = 0; nt < 4; nt++) {
    int gn = n0 + wn * 64 + nt * 16 + lr;
    float bv = bias[gn];
#pragma unroll
    for (int mt = 0; mt < 4; mt++)
#pragma unroll
      for (int r = 0; r < 4; r++) {
        int gm = m0 + wm * 64 + mt * 16 + lq * 4 + r;
        out[(size_t)gm * 1024 + gn] = acc[mt][nt][r] + bv;
      }
  }
}

// ---------------- flash attention: qg=4 (64 q rows/wave, 256/block) ----------------
// Block = 4 waves = 256 q rows. KV-step 64, double-buffered K/V in LDS.
// Per kv-64: same 16KB staged per block as before, but 2x MFMA/VALU work ->
// 2x ILP chains per K-fragment, half the staging per output. Grid 512.

__global__ __launch_bounds__(256) void attn_kernel(
    const u16* __restrict__ Qb, const u16* __restrict__ Kb,
    const u16* __restrict__ Vt, u16* __restrict__ Ob) {
  const int S = 2048, D = 64;
  __shared__ short8 lK[2][512];            // 16 KB
  __shared__ short8 lV[2][512];            // 16 KB
  __shared__ __align__(16) u32 pb[4][16][20];   // 5 KB
  int tid = threadIdx.x;
  int w = tid >> 6, l = tid & 63, lr = l & 15, lq = l >> 4;
  int gid = blockIdx.x;
  int xcd = gid & 7, j = gid >> 3;        // j in [0,64)
  int bh = xcd * 8 + (j >> 3);            // qblk-major within bh
  int qblk = j & 7;                       // 0..7 (256 rows each)
  int q0 = qblk * 256 + w * 64;
  const u16* Qh = Qb + (size_t)bh * S * D;
  const u16* Kh = Kb + (size_t)bh * S * D;
  const u16* Vh = Vt + (size_t)bh * D * S;

  short8 qf[4][2];
#pragma unroll
  for (int qg = 0; qg < 4; qg++) {
    qf[qg][0] = *(const short8*)(Qh + (q0 + qg * 16 + lr) * D + lq * 8);
    qf[qg][1] = *(const short8*)(Qh + (q0 + qg * 16 + lr) * D + 32 + lq * 8);
  }

  float ls[4][4] = {};
  float4_ o[4][4] = {};

  const u16* kg = Kh + (size_t)(((w >> 1) << 5) + 2 * lr + (w & 1)) * D + lq * 8;
  const u16* vg = Vh + (size_t)(w * 16 + lr) * S + lq * 8;

  auto stage = [&](int buf, int kv0) {
    async_cp16(kg + (size_t)kv0 * D, &lK[buf][(w * 2 + 0) * 64 + l]);
    async_cp16(kg + (size_t)kv0 * D + 32, &lK[buf][(w * 2 + 1) * 64 + l]);
    async_cp16(vg + kv0, &lV[buf][(w * 2 + 0) * 64 + l]);
    async_cp16(vg + kv0 + 32, &lV[buf][(w * 2 + 1) * 64 + l]);
  };

  auto compute = [&](int buf) {
#pragma unroll
    for (int sub = 0; sub < 2; sub++) {
      short8 ke0 = lK[buf][((sub * 2 + 0) * 2 + 0) * 64 + l];  // even rows, d 0..31
      short8 ke1 = lK[buf][((sub * 2 + 0) * 2 + 1) * 64 + l];  // even rows, d 32..63
      short8 ko0 = lK[buf][((sub * 2 + 1) * 2 + 0) * 64 + l];  // odd rows,  d 0..31
      short8 ko1 = lK[buf][((sub * 2 + 1) * 2 + 1) * 64 + l];  // odd rows,  d 32..63
#pragma unroll
      for (int qg = 0; qg < 4; qg++) {
        float4_ z = {0.f, 0.f, 0.f, 0.f};
        float4_ s0 = __builtin_amdgcn_mfma_f32_16x16x32_bf16(qf[qg][0], ke0, z, 0, 0, 0);
        s0 = __builtin_amdgcn_mfma_f32_16x16x32_bf16(qf[qg][1], ke1, s0, 0, 0, 0);
        float4_ s1 = __builtin_amdgcn_mfma_f32_16x16x32_bf16(qf[qg][0], ko0, z, 0, 0, 0);
        s1 = __builtin_amdgcn_mfma_f32_16x16x32_bf16(qf[qg][1], ko1, s1, 0, 0, 0);
#pragma unroll
        for (int r = 0; r < 4; r++) {
          float p0 = fexp2(s0[r]);
          float p1 = fexp2(s1[r]);
          u32 pk = pk_trunc(p0, p1);
          ls[qg][r] = accum_pk(pk, ls[qg][r]);  // rounded values: bias cancels
          pb[w][lq * 4 + r][lr] = pk;
        }
        short8 pa = *(const short8*)&pb[w][lr][lq * 4];  // A-frag: row lr, kv lq*8..+7
#pragma unroll
        for (int dt = 0; dt < 4; dt++)
          o[qg][dt] = __builtin_amdgcn_mfma_f32_16x16x32_bf16(
              pa, lV[buf][(dt * 2 + sub) * 64 + l], o[qg][dt], 0, 0, 0);
      }
    }
  };

  stage(0, 0);
  for (int kv0 = 0; kv0 < S; kv0 += 128) {
    __syncthreads();
    stage(1, kv0 + 64);
    compute(0);
    __syncthreads();
    if (kv0 + 128 < S) stage(0, kv0 + 128);
    compute(1);
  }

  int b = bh >> 4, h = bh & 15;
#pragma unroll
  for (int qg = 0; qg < 4; qg++) {
    float inv[4];
#pragma unroll
    for (int r = 0; r < 4; r++) {
      float s = ls[qg][r];
#pragma unroll
      for (int off = 1; off < 16; off <<= 1) s += __shfl_xor(s, off, 64);
      inv[r] = 1.0f / s;
    }
#pragma unroll
    for (int dt = 0; dt < 4; dt++)
#pragma unroll
      for (int r = 0; r < 4; r++) {
        int s_ = q0 + qg * 16 + lq * 4 + r;
        Ob[((size_t)(b * 2048 + s_)) * 1024 + h * 64 + dt * 16 + lr] =
            f2b(o[qg][dt][r] * inv[r]);
      }
  }
}

// ---------------- launch ----------------

extern "C" void kernel_launch(void* const* d_in, const int* in_sizes, int n_in,
                              void* d_out, int out_size, void* d_ws, size_t ws_size,
                              hipStream_t stream) {
  const float* x     = (const float*)d_in[0];   // [4,2048,1024]
  const float* w_qkv = (const float*)d_in[1];   // [1024,3072]
  const float* w_out = (const float*)d_in[2];   // [1024,1024]
  const float* b_out = (const float*)d_in[3];   // [1024]
  float* out = (float*)d_out;

  char* ws = (char*)d_ws;
  u16* Xb  = (u16*)(ws);                    // 16 MB (x bf16; reused as O)
  u16* Wqt = (u16*)(ws + (16u << 20));      // 6 MB  (w_qkv^T bf16)
  u16* Wot = (u16*)(ws + (22u << 20));      // 2 MB  (w_out^T bf16)
  u16* QKV = (u16*)(ws + (24u << 20));      // 48 MB: Q | K | V  (each [b,h,s,d])
  u16* Qb  = QKV;
  u16* Kb  = QKV + 8388608;
  u16* Vb  = QKV + 16777216;
  u16* Vt  = (u16*)(ws + (72u << 20));      // 16 MB [b,h,d,s] -> 88 MB total
  u16* Ob  = Xb;                            // O overwrites Xb

  prepass_kernel<<<12288, 256, 0, stream>>>(x, Xb, w_qkv, Wqt, w_out, Wot);
  gemm_qkv_kernel<<<1536, 256, 0, stream>>>(Xb, Wqt, QKV);
  transpose_v<<<dim3(32, 64), 256, 0, stream>>>(Vb, Vt);
  attn_kernel<<<512, 256, 0, stream>>>(Qb, Kb, Vt, Ob);
  gemm_out_kernel<<<512, 256, 0, stream>>>(Ob, Wot, b_out, out);
}

// Round 7
// 337.336 us; speedup vs baseline: 1.1201x; 1.1201x over previous
//
#include <hip/hip_runtime.h>
#include <cstdint>
#include <cstddef>

// MI355X self-attention: B=4 S=2048 E=1024 H=16 D=64
// R14 = R13 resubmit (bench died to container infra failure, same signature
//  as R3 which resolved on resubmission; kernel re-audited: math, sync, and
//  resource checks all pass).
// R13: attn qg=2 geometry rebuilt with swapped QK^T (A=K, B=Q) + kv-permuted
//  K fragments so softmax P is assembled IN REGISTERS: lane's own packed
//  words are A-frag W0,W1; W2,W3 arrive via two shfl_xor(32). Removes the
//  per-qg LDS pb write->lgkmcnt(0)->read serialization and all 2.1M
//  bank-conflict cycles; pb deleted (LDS 37.9->32.8KB). MFMA/exp/pack counts
//  and K/V staging volume unchanged. GEMMs = R7 exact (best measured).

typedef __attribute__((ext_vector_type(8))) short short8;   // 8 x bf16
typedef __attribute__((ext_vector_type(4))) float float4_;
typedef __attribute__((ext_vector_type(4))) unsigned int u32x4;
typedef unsigned int u32;
typedef unsigned short u16;

__device__ __forceinline__ u16 f2b(float f) {
  u32 u = __float_as_uint(f);
  u += 0x7FFFu + ((u >> 16) & 1u);   // RNE
  return (u16)(u >> 16);
}

__device__ __forceinline__ float fexp2(float x) {
#if __has_builtin(__builtin_amdgcn_exp2f)
  return __builtin_amdgcn_exp2f(x);   // bare v_exp_f32
#else
  return exp2f(x);
#endif
}

// pack (lo,hi) floats -> bf16x2 by truncation (1 v_perm)
__device__ __forceinline__ u32 pk_trunc(float lo, float hi) {
#if __has_builtin(__builtin_amdgcn_perm)
  return __builtin_amdgcn_perm(__float_as_uint(hi), __float_as_uint(lo), 0x07060302);
#else
  return (__float_as_uint(hi) & 0xFFFF0000u) | (__float_as_uint(lo) >> 16);
#endif
}

#if __has_builtin(__builtin_amdgcn_fdot2_f32_bf16)
typedef __bf16 bf16x2 __attribute__((ext_vector_type(2)));
__device__ __forceinline__ float accum_pk(u32 pk, float acc) {
  bf16x2 p = __builtin_bit_cast(bf16x2, pk);
  bf16x2 one = __builtin_bit_cast(bf16x2, (u32)0x3F803F80u);
  return __builtin_amdgcn_fdot2_f32_bf16(p, one, acc, false);
}
#else
__device__ __forceinline__ float accum_pk(u32 pk, float acc) {
  return acc + __uint_as_float(pk << 16) + __uint_as_float(pk & 0xFFFF0000u);
}
#endif

// async global->LDS, 16B per lane; LDS dst must be wave-uniform base + lane*16
__device__ __forceinline__ void async_cp16(const void* g, void* l) {
  __builtin_amdgcn_global_load_lds(
      (const __attribute__((address_space(1))) u32*)g,
      (__attribute__((address_space(3))) u32*)l, 16, 0, 0);
}

// ---------------- fused pre-pass ----------------
// blocks [0,8192): cvt x->bf16; [8192,11264): transpose w_qkv; rest: w_out.

__device__ __forceinline__ void transpose_block(const float* __restrict__ in,
                                                u16* __restrict__ out,
                                                int R, int C, int bx, int by,
                                                float t[32][33]) {
  int tx = threadIdx.x & 31, ty = threadIdx.x >> 5;
  int r0 = by * 32, c0 = bx * 32;
#pragma unroll
  for (int k = 0; k < 4; k++)
    t[ty + 8 * k][tx] = in[(size_t)(r0 + ty + 8 * k) * C + c0 + tx];
  __syncthreads();
#pragma unroll
  for (int k = 0; k < 4; k++)
    out[(size_t)(c0 + ty + 8 * k) * R + r0 + tx] = f2b(t[tx][ty + 8 * k]);
}

__global__ void prepass_kernel(const float* __restrict__ x, u16* __restrict__ Xb,
                               const float* __restrict__ wqkv, u16* __restrict__ Wqt,
                               const float* __restrict__ wout, u16* __restrict__ Wot) {
  __shared__ float t[32][33];
  int gid = blockIdx.x;
  if (gid < 8192) {
    int i = gid * 256 + threadIdx.x;
    float4 v = ((const float4*)x)[i];
    uint2 p;
    p.x = (u32)f2b(v.x) | ((u32)f2b(v.y) << 16);
    p.y = (u32)f2b(v.z) | ((u32)f2b(v.w) << 16);
    ((uint2*)Xb)[i] = p;
  } else if (gid < 11264) {
    int j = gid - 8192;
    transpose_block(wqkv, Wqt, 1024, 3072, j % 96, j / 96, t);
  } else {
    int j = gid - 11264;
    transpose_block(wout, Wot, 1024, 1024, j % 32, j / 32, t);
  }
}

// V[bh][s][d] bf16 -> Vt[bh][d][s] bf16. 64x64 tiles. grid (32, 64), block 256.
__global__ void transpose_v(const u16* __restrict__ V, u16* __restrict__ Vt) {
  __shared__ u16 t[64][80];
  int bh = blockIdx.y, s0 = blockIdx.x * 64;
  const u16* Vh = V + (size_t)bh * 2048 * 64;
  u16* Vth = Vt + (size_t)bh * 64 * 2048;
  int tr = threadIdx.x >> 3;            // 0..31
  int tc = (threadIdx.x & 7) * 8;       // 0..56 step 8
#pragma unroll
  for (int p = 0; p < 2; p++) {
    int r = p * 32 + tr;
    *(uint4*)&t[r][tc] = *(const uint4*)(Vh + (size_t)(s0 + r) * 64 + tc);
  }
  __syncthreads();
#pragma unroll
  for (int p = 0; p < 2; p++) {
    int d = p * 32 + tr;
    u16 tmp[8];
#pragma unroll
    for (int k = 0; k < 8; k++) tmp[k] = t[tc + k][d];
    *(uint4*)(Vth + (size_t)d * 2048 + s0 + tc) = *(uint4*)tmp;
  }
}

// ---------------- GEMM kernels (R7 exact: 128x128 tile, 16x16x32 bf16 MFMA) -------

__global__ __launch_bounds__(256) void gemm_qkv_kernel(
    const u16* __restrict__ A, const u16* __restrict__ Bt,
    u16* __restrict__ QKV) {   // QKV = 3 x 16MB consecutive [b,h,s,d] buffers
  const int K = 1024;
  __shared__ short8 lA[2][512];   // 16 KB
  __shared__ short8 lB[2][512];   // 16 KB
  int tid = threadIdx.x;
  int w = tid >> 6, l = tid & 63, lr = l & 15, lq = l >> 4;
  int gid = blockIdx.x;
  int xcd = gid & 7, j = gid >> 3;     // 192 blocks per XCD
  int yloc = j & 7, xt = j >> 3;       // y-minor: 8 y per xt before next B-tile
  int m0 = (xcd * 8 + yloc) * 128, n0 = xt * 128;
  int wm = w & 1, wn = w >> 1;
  float4_ acc[4][4] = {};

  const u16* gA0 = A + (size_t)(m0 + w * 32 + lr) * K + lq * 8;
  const u16* gA1 = gA0 + 16 * K;
  const u16* gB0 = Bt + (size_t)(n0 + w * 32 + lr) * K + lq * 8;
  const u16* gB1 = gB0 + 16 * K;

  auto stage = [&](int buf, int k0) {
    async_cp16(gA0 + k0, &lA[buf][(w * 2 + 0) * 64 + l]);
    async_cp16(gA1 + k0, &lA[buf][(w * 2 + 1) * 64 + l]);
    async_cp16(gB0 + k0, &lB[buf][(w * 2 + 0) * 64 + l]);
    async_cp16(gB1 + k0, &lB[buf][(w * 2 + 1) * 64 + l]);
  };
  auto compute = [&](int buf) {
    short8 af[4], bf[4];
#pragma unroll
    for (int t = 0; t < 4; t++) {
      af[t] = lA[buf][(wm * 4 + t) * 64 + l];
      bf[t] = lB[buf][(wn * 4 + t) * 64 + l];
    }
#pragma unroll
    for (int mt = 0; mt < 4; mt++)
#pragma unroll
      for (int nt = 0; nt < 4; nt++)
        acc[mt][nt] = __builtin_amdgcn_mfma_f32_16x16x32_bf16(af[mt], bf[nt], acc[mt][nt], 0, 0, 0);
  };

  stage(0, 0);
  for (int k0 = 0; k0 < K; k0 += 64) {
    __syncthreads();
    stage(1, k0 + 32);
    compute(0);
    __syncthreads();
    if (k0 + 64 < K) stage(0, k0 + 64);
    compute(1);
  }

  const float qsc = 0.18033688011112042f;  // d^-0.5 * log2(e)
#pragma unroll
  for (int nt = 0; nt < 4; nt++) {
    int gn = n0 + wn * 64 + nt * 16 + lr;
    int sel = gn >> 10;
    int h = (gn >> 6) & 15;
    int d = gn & 63;
    float sc = (sel == 0) ? qsc : 1.0f;
    u16* dst = QKV + (size_t)sel * 8388608 + ((size_t)h * 2048) * 64 + d;
#pragma unroll
    for (int mt = 0; mt < 4; mt++) {
#pragma unroll
      for (int r = 0; r < 4; r++) {
        int gm = m0 + wm * 64 + mt * 16 + lq * 4 + r;
        int b = gm >> 11, s = gm & 2047;
        dst[((size_t)b * 16 * 2048 + s) * 64] = f2b(acc[mt][nt][r] * sc);
      }
    }
  }
}

__global__ __launch_bounds__(256) void gemm_out_kernel(
    const u16* __restrict__ A, const u16* __restrict__ Bt,
    const float* __restrict__ bias, float* __restrict__ out) {
  const int K = 1024;
  __shared__ short8 lA[2][512];
  __shared__ short8 lB[2][512];
  int tid = threadIdx.x;
  int w = tid >> 6, l = tid & 63, lr = l & 15, lq = l >> 4;
  int gid = blockIdx.x;
  int xcd = gid & 7, j = gid >> 3;     // 64 blocks per XCD
  int yloc = j & 7, xt = j >> 3;       // 8 y x 8 x per XCD
  int m0 = (xcd * 8 + yloc) * 128, n0 = xt * 128;
  int wm = w & 1, wn = w >> 1;
  float4_ acc[4][4] = {};

  const u16* gA0 = A + (size_t)(m0 + w * 32 + lr) * K + lq * 8;
  const u16* gA1 = gA0 + 16 * K;
  const u16* gB0 = Bt + (size_t)(n0 + w * 32 + lr) * K + lq * 8;
  const u16* gB1 = gB0 + 16 * K;

  auto stage = [&](int buf, int k0) {
    async_cp16(gA0 + k0, &lA[buf][(w * 2 + 0) * 64 + l]);
    async_cp16(gA1 + k0, &lA[buf][(w * 2 + 1) * 64 + l]);
    async_cp16(gB0 + k0, &lB[buf][(w * 2 + 0) * 64 + l]);
    async_cp16(gB1 + k0, &lB[buf][(w * 2 + 1) * 64 + l]);
  };
  auto compute = [&](int buf) {
    short8 af[4], bf[4];
#pragma unroll
    for (int t = 0; t < 4; t++) {
      af[t] = lA[buf][(wm * 4 + t) * 64 + l];
      bf[t] = lB[buf][(wn * 4 + t) * 64 + l];
    }
#pragma unroll
    for (int mt = 0; mt < 4; mt++)
#pragma unroll
      for (int nt = 0; nt < 4; nt++)
        acc[mt][nt] = __builtin_amdgcn_mfma_f32_16x16x32_bf16(af[mt], bf[nt], acc[mt][nt], 0, 0, 0);
  };

  stage(0, 0);
  for (int k0 = 0; k0 < K; k0 += 64) {
    __syncthreads();
    stage(1, k0 + 32);
    compute(0);
    __syncthreads();
    if (k0 + 64 < K) stage(0, k0 + 64);
    compute(1);
  }

#pragma unroll
  for (int nt = 0; nt < 4; nt++) {
    int gn = n0 + wn * 64 + nt * 16 + lr;
    float bv = bias[gn];
#pragma unroll
    for (int mt = 0; mt < 4; mt++)
#pragma unroll
      for (int r = 0; r < 4; r++) {
        int gm = m0 + wm * 64 + mt * 16 + lq * 4 + r;
        out[(size_t)gm * 1024 + gn] = acc[mt][nt][r] + bv;
      }
  }
}

// ---------------- flash attention: swapped QK^T, in-register P ----------------
// Block = 4 waves = 128 q rows (32/wave), KV-step 64, double-buffered. Grid 1024.
// S = mfma(A=K_frag, B=Q_frag): output lane (lq,lr) holds S[kv][q=lr] with
// kv = sub*32 + pi(lq*4+r). K rows are PERMUTED at staging:
//   pi0(i) = 8*(i>>2) + (i&3)        (S0: f=0,1 -> kv 8*lq + r)
//   pi1(i) = 8*((i>>2)^2) + 4 + (i&3) (S1: f=2,3 -> kv 8*(lq^2)+4+r)
// so after exp+pack, lane's own w0,w1 = PV A-frag words kv 8lq..+3 and the
// partner's y0,y1 (kv 8lq+4..+7) arrive via shfl_xor(32). No LDS roundtrip.
// Row-sum is lane-local -> ls[qg] scalar; reduced xor16+xor32 at the end.

__global__ __launch_bounds__(256) void attn_kernel(
    const u16* __restrict__ Qb, const u16* __restrict__ Kb,
    const u16* __restrict__ Vt, u16* __restrict__ Ob) {
  const int S = 2048, D = 64;
  __shared__ short8 lK[2][512];            // 16 KB
  __shared__ short8 lV[2][512];            // 16 KB
  int tid = threadIdx.x;
  int w = tid >> 6, l = tid & 63, lr = l & 15, lq = l >> 4;
  int gid = blockIdx.x;
  int xcd = gid & 7, j = gid >> 3;        // j in [0,128)
  int bh = xcd * 8 + (j >> 4);            // qblk-major: consecutive j share bh
  int qblk = j & 15;                      // 0..15
  int q0 = qblk * 128 + w * 32;
  const u16* Qh = Qb + (size_t)bh * S * D;
  const u16* Kh = Kb + (size_t)bh * S * D;
  const u16* Vh = Vt + (size_t)bh * D * S;

  short8 qf[2][2];
#pragma unroll
  for (int qg = 0; qg < 2; qg++) {
    qf[qg][0] = *(const short8*)(Qh + (q0 + qg * 16 + lr) * D + lq * 8);
    qf[qg][1] = *(const short8*)(Qh + (q0 + qg * 16 + lr) * D + 32 + lq * 8);
  }

  float ls[2] = {};
  float4_ o[2][4] = {};

  // K staging sources: chunk c = w*2+i; sub = w>>1; f = (w&1)*2+i.
  // lane supplies K[kv0 + sub*32 + pi_f(lr)][(f&1)*32 + lq*8 ..+8]
  const u16* kgsrc[2];
#pragma unroll
  for (int i = 0; i < 2; i++) {
    int f = (w & 1) * 2 + i;
    int sub = w >> 1;
    int kvl = sub * 32 + ((f < 2) ? (8 * (lr >> 2) + (lr & 3))
                                  : (8 * ((lr >> 2) ^ 2) + 4 + (lr & 3)));
    kgsrc[i] = Kh + (size_t)kvl * D + (f & 1) * 32 + lq * 8;
  }
  const u16* vg = Vh + (size_t)(w * 16 + lr) * S + lq * 8;

  auto stage = [&](int buf, int kv0) {
    async_cp16(kgsrc[0] + (size_t)kv0 * D, &lK[buf][(w * 2 + 0) * 64 + l]);
    async_cp16(kgsrc[1] + (size_t)kv0 * D, &lK[buf][(w * 2 + 1) * 64 + l]);
    async_cp16(vg + kv0, &lV[buf][(w * 2 + 0) * 64 + l]);
    async_cp16(vg + kv0 + 32, &lV[buf][(w * 2 + 1) * 64 + l]);
  };

  auto compute = [&](int buf) {
#pragma unroll
    for (int sub = 0; sub < 2; sub++) {
      short8 kf0 = lK[buf][(sub * 4 + 0) * 64 + l];   // pi0 rows, d 0..31
      short8 kf1 = lK[buf][(sub * 4 + 1) * 64 + l];   // pi0 rows, d 32..63
      short8 kf2 = lK[buf][(sub * 4 + 2) * 64 + l];   // pi1 rows, d 0..31
      short8 kf3 = lK[buf][(sub * 4 + 3) * 64 + l];   // pi1 rows, d 32..63
#pragma unroll
      for (int qg = 0; qg < 2; qg++) {
        float4_ z = {0.f, 0.f, 0.f, 0.f};
        float4_ s0 = __builtin_amdgcn_mfma_f32_16x16x32_bf16(kf0, qf[qg][0], z, 0, 0, 0);
        s0 = __builtin_amdgcn_mfma_f32_16x16x32_bf16(kf1, qf[qg][1], s0, 0, 0, 0);
        float4_ s1 = __builtin_amdgcn_mfma_f32_16x16x32_bf16(kf2, qf[qg][0], z, 0, 0, 0);
        s1 = __builtin_amdgcn_mfma_f32_16x16x32_bf16(kf3, qf[qg][1], s1, 0, 0, 0);
        float p00 = fexp2(s0[0]), p01 = fexp2(s0[1]);
        float p02 = fexp2(s0[2]), p03 = fexp2(s0[3]);
        float p10 = fexp2(s1[0]), p11 = fexp2(s1[1]);
        float p12 = fexp2(s1[2]), p13 = fexp2(s1[3]);
        u32 w0 = pk_trunc(p00, p01), w1 = pk_trunc(p02, p03);
        u32 y0 = pk_trunc(p10, p11), y1 = pk_trunc(p12, p13);
        float a = ls[qg];
        a = accum_pk(w0, a); a = accum_pk(w1, a);
        a = accum_pk(y0, a); a = accum_pk(y1, a);
        ls[qg] = a;
        u32 W2 = (u32)__shfl_xor((int)y0, 32, 64);   // kv 8lq+4,+5 (from lq^2)
        u32 W3 = (u32)__shfl_xor((int)y1, 32, 64);   // kv 8lq+6,+7
        u32x4 pw = {w0, w1, W2, W3};
        short8 pa = __builtin_bit_cast(short8, pw);  // A-frag: P[q=lr][kv=8lq..+7]
#pragma unroll
        for (int dt = 0; dt < 4; dt++)
          o[qg][dt] = __builtin_amdgcn_mfma_f32_16x16x32_bf16(
              pa, lV[buf][(dt * 2 + sub) * 64 + l], o[qg][dt], 0, 0, 0);
      }
    }
  };

  stage(0, 0);
  for (int kv0 = 0; kv0 < S; kv0 += 128) {
    __syncthreads();
    stage(1, kv0 + 64);
    compute(0);
    __syncthreads();
    if (kv0 + 128 < S) stage(0, kv0 + 128);
    compute(1);
  }

  int b = bh >> 4, h = bh & 15;
#pragma unroll
  for (int qg = 0; qg < 2; qg++) {
    float s = ls[qg];
    s += __shfl_xor(s, 16, 64);
    s += __shfl_xor(s, 32, 64);   // full denom for q = q0+qg*16+lr, all lanes of column lr
    float inv[4];
#pragma unroll
    for (int r = 0; r < 4; r++)
      inv[r] = 1.0f / __shfl(s, lq * 4 + r, 64);   // denom for q-row lq*4+r
#pragma unroll
    for (int dt = 0; dt < 4; dt++)
#pragma unroll
      for (int r = 0; r < 4; r++) {
        int s_ = q0 + qg * 16 + lq * 4 + r;
        Ob[((size_t)(b * 2048 + s_)) * 1024 + h * 64 + dt * 16 + lr] =
            f2b(o[qg][dt][r] * inv[r]);
      }
  }
}

// ---------------- launch ----------------

extern "C" void kernel_launch(void* const* d_in, const int* in_sizes, int n_in,
                              void* d_out, int out_size, void* d_ws, size_t ws_size,
                              hipStream_t stream) {
  const float* x     = (const float*)d_in[0];   // [4,2048,1024]
  const float* w_qkv = (const float*)d_in[1];   // [1024,3072]
  const float* w_out = (const float*)d_in[2];   // [1024,1024]
  const float* b_out = (const float*)d_in[3];   // [1024]
  float* out = (float*)d_out;

  char* ws = (char*)d_ws;
  u16* Xb  = (u16*)(ws);                    // 16 MB (x bf16; reused as O)
  u16* Wqt = (u16*)(ws + (16u << 20));      // 6 MB  (w_qkv^T bf16)
  u16* Wot = (u16*)(ws + (22u << 20));      // 2 MB  (w_out^T bf16)
  u16* QKV = (u16*)(ws + (24u << 20));      // 48 MB: Q | K | V  (each [b,h,s,d])
  u16* Qb  = QKV;
  u16* Kb  = QKV + 8388608;
  u16* Vb  = QKV + 16777216;
  u16* Vt  = (u16*)(ws + (72u << 20));      // 16 MB [b,h,d,s] -> 88 MB total
  u16* Ob  = Xb;                            // O overwrites Xb

  prepass_kernel<<<12288, 256, 0, stream>>>(x, Xb, w_qkv, Wqt, w_out, Wot);
  gemm_qkv_kernel<<<1536, 256, 0, stream>>>(Xb, Wqt, QKV);
  transpose_v<<<dim3(32, 64), 256, 0, stream>>>(Vb, Vt);
  attn_kernel<<<1024, 256, 0, stream>>>(Qb, Kb, Vt, Ob);
  gemm_out_kernel<<<512, 256, 0, stream>>>(Ob, Wot, b_out, out);
}

// Round 8
// 326.859 us; speedup vs baseline: 1.1560x; 1.0321x over previous
//
#include <hip/hip_runtime.h>
#include <cstdint>
#include <cstddef>

// MI355X self-attention: B=4 S=2048 E=1024 H=16 D=64
// R15: (1) transpose_v DELETED — gemm_qkv V-blocks (n0>=2048) write V^T
//  directly to Vt[bh][d][s]: per (nt,mt) the 4 r-values are s-consecutive ->
//  one uint2 store, 32B segments, 16 stores/thread (vs 64 before). Saves the
//  32MB transpose traffic + a launch gap. (2) attn __launch_bounds__(256,4):
//  force >=4 waves/SIMD (4 blocks/CU) — R14 showed attn stall-bound at 23%
//  occupancy (2 blocks/CU). GEMM core loop + attn math unchanged from R14.

typedef __attribute__((ext_vector_type(8))) short short8;   // 8 x bf16
typedef __attribute__((ext_vector_type(4))) float float4_;
typedef __attribute__((ext_vector_type(4))) unsigned int u32x4;
typedef unsigned int u32;
typedef unsigned short u16;

__device__ __forceinline__ u16 f2b(float f) {
  u32 u = __float_as_uint(f);
  u += 0x7FFFu + ((u >> 16) & 1u);   // RNE
  return (u16)(u >> 16);
}

__device__ __forceinline__ float fexp2(float x) {
#if __has_builtin(__builtin_amdgcn_exp2f)
  return __builtin_amdgcn_exp2f(x);   // bare v_exp_f32
#else
  return exp2f(x);
#endif
}

// pack (lo,hi) floats -> bf16x2 by truncation (1 v_perm)
__device__ __forceinline__ u32 pk_trunc(float lo, float hi) {
#if __has_builtin(__builtin_amdgcn_perm)
  return __builtin_amdgcn_perm(__float_as_uint(hi), __float_as_uint(lo), 0x07060302);
#else
  return (__float_as_uint(hi) & 0xFFFF0000u) | (__float_as_uint(lo) >> 16);
#endif
}

#if __has_builtin(__builtin_amdgcn_fdot2_f32_bf16)
typedef __bf16 bf16x2 __attribute__((ext_vector_type(2)));
__device__ __forceinline__ float accum_pk(u32 pk, float acc) {
  bf16x2 p = __builtin_bit_cast(bf16x2, pk);
  bf16x2 one = __builtin_bit_cast(bf16x2, (u32)0x3F803F80u);
  return __builtin_amdgcn_fdot2_f32_bf16(p, one, acc, false);
}
#else
__device__ __forceinline__ float accum_pk(u32 pk, float acc) {
  return acc + __uint_as_float(pk << 16) + __uint_as_float(pk & 0xFFFF0000u);
}
#endif

// async global->LDS, 16B per lane; LDS dst must be wave-uniform base + lane*16
__device__ __forceinline__ void async_cp16(const void* g, void* l) {
  __builtin_amdgcn_global_load_lds(
      (const __attribute__((address_space(1))) u32*)g,
      (__attribute__((address_space(3))) u32*)l, 16, 0, 0);
}

// ---------------- fused pre-pass ----------------
// blocks [0,8192): cvt x->bf16; [8192,11264): transpose w_qkv; rest: w_out.

__device__ __forceinline__ void transpose_block(const float* __restrict__ in,
                                                u16* __restrict__ out,
                                                int R, int C, int bx, int by,
                                                float t[32][33]) {
  int tx = threadIdx.x & 31, ty = threadIdx.x >> 5;
  int r0 = by * 32, c0 = bx * 32;
#pragma unroll
  for (int k = 0; k < 4; k++)
    t[ty + 8 * k][tx] = in[(size_t)(r0 + ty + 8 * k) * C + c0 + tx];
  __syncthreads();
#pragma unroll
  for (int k = 0; k < 4; k++)
    out[(size_t)(c0 + ty + 8 * k) * R + r0 + tx] = f2b(t[tx][ty + 8 * k]);
}

__global__ void prepass_kernel(const float* __restrict__ x, u16* __restrict__ Xb,
                               const float* __restrict__ wqkv, u16* __restrict__ Wqt,
                               const float* __restrict__ wout, u16* __restrict__ Wot) {
  __shared__ float t[32][33];
  int gid = blockIdx.x;
  if (gid < 8192) {
    int i = gid * 256 + threadIdx.x;
    float4 v = ((const float4*)x)[i];
    uint2 p;
    p.x = (u32)f2b(v.x) | ((u32)f2b(v.y) << 16);
    p.y = (u32)f2b(v.z) | ((u32)f2b(v.w) << 16);
    ((uint2*)Xb)[i] = p;
  } else if (gid < 11264) {
    int j = gid - 8192;
    transpose_block(wqkv, Wqt, 1024, 3072, j % 96, j / 96, t);
  } else {
    int j = gid - 11264;
    transpose_block(wout, Wot, 1024, 1024, j % 32, j / 32, t);
  }
}

// ---------------- GEMM kernels (R7 core: 128x128 tile, 16x16x32 bf16 MFMA) -------

__global__ __launch_bounds__(256) void gemm_qkv_kernel(
    const u16* __restrict__ A, const u16* __restrict__ Bt,
    u16* __restrict__ QKV,     // Q | K regions used; V written to Vt instead
    u16* __restrict__ Vt) {    // [b,h,d,s]
  const int K = 1024;
  __shared__ short8 lA[2][512];   // 16 KB
  __shared__ short8 lB[2][512];   // 16 KB
  int tid = threadIdx.x;
  int w = tid >> 6, l = tid & 63, lr = l & 15, lq = l >> 4;
  int gid = blockIdx.x;
  int xcd = gid & 7, j = gid >> 3;     // 192 blocks per XCD
  int yloc = j & 7, xt = j >> 3;       // y-minor: 8 y per xt before next B-tile
  int m0 = (xcd * 8 + yloc) * 128, n0 = xt * 128;
  int wm = w & 1, wn = w >> 1;
  float4_ acc[4][4] = {};

  const u16* gA0 = A + (size_t)(m0 + w * 32 + lr) * K + lq * 8;
  const u16* gA1 = gA0 + 16 * K;
  const u16* gB0 = Bt + (size_t)(n0 + w * 32 + lr) * K + lq * 8;
  const u16* gB1 = gB0 + 16 * K;

  auto stage = [&](int buf, int k0) {
    async_cp16(gA0 + k0, &lA[buf][(w * 2 + 0) * 64 + l]);
    async_cp16(gA1 + k0, &lA[buf][(w * 2 + 1) * 64 + l]);
    async_cp16(gB0 + k0, &lB[buf][(w * 2 + 0) * 64 + l]);
    async_cp16(gB1 + k0, &lB[buf][(w * 2 + 1) * 64 + l]);
  };
  auto compute = [&](int buf) {
    short8 af[4], bf[4];
#pragma unroll
    for (int t = 0; t < 4; t++) {
      af[t] = lA[buf][(wm * 4 + t) * 64 + l];
      bf[t] = lB[buf][(wn * 4 + t) * 64 + l];
    }
#pragma unroll
    for (int mt = 0; mt < 4; mt++)
#pragma unroll
      for (int nt = 0; nt < 4; nt++)
        acc[mt][nt] = __builtin_amdgcn_mfma_f32_16x16x32_bf16(af[mt], bf[nt], acc[mt][nt], 0, 0, 0);
  };

  stage(0, 0);
  for (int k0 = 0; k0 < K; k0 += 64) {
    __syncthreads();
    stage(1, k0 + 32);
    compute(0);
    __syncthreads();
    if (k0 + 64 < K) stage(0, k0 + 64);
    compute(1);
  }

  if (n0 < 2048) {
    // Q (scaled) / K: [b,h,s,d] scattered u16 stores (R7 pattern)
    const float qsc = 0.18033688011112042f;  // d^-0.5 * log2(e)
#pragma unroll
    for (int nt = 0; nt < 4; nt++) {
      int gn = n0 + wn * 64 + nt * 16 + lr;
      int sel = gn >> 10;
      int h = (gn >> 6) & 15;
      int d = gn & 63;
      float sc = (sel == 0) ? qsc : 1.0f;
      u16* dst = QKV + (size_t)sel * 8388608 + ((size_t)h * 2048) * 64 + d;
#pragma unroll
      for (int mt = 0; mt < 4; mt++) {
#pragma unroll
        for (int r = 0; r < 4; r++) {
          int gm = m0 + wm * 64 + mt * 16 + lq * 4 + r;
          int b = gm >> 11, s = gm & 2047;
          dst[((size_t)b * 16 * 2048 + s) * 64] = f2b(acc[mt][nt][r] * sc);
        }
      }
    }
  } else {
    // V: write V^T directly. b uniform per block (128 rows within one b);
    // per (nt): h,d uniform per lane; 4 r-values are s-consecutive -> uint2.
    int b = m0 >> 11;
    int sbase = (m0 & 2047) + wm * 64;
#pragma unroll
    for (int nt = 0; nt < 4; nt++) {
      int gn = n0 + wn * 64 + nt * 16 + lr;
      int h = (gn >> 6) & 15;
      int d = gn & 63;
      u16* dstV = Vt + (size_t)(b * 16 + h) * 131072 + (size_t)d * 2048 + sbase;
#pragma unroll
      for (int mt = 0; mt < 4; mt++) {
        u16 tmp[4];
#pragma unroll
        for (int r = 0; r < 4; r++) tmp[r] = f2b(acc[mt][nt][r]);
        *(uint2*)(dstV + mt * 16 + lq * 4) = *(uint2*)tmp;
      }
    }
  }
}

__global__ __launch_bounds__(256) void gemm_out_kernel(
    const u16* __restrict__ A, const u16* __restrict__ Bt,
    const float* __restrict__ bias, float* __restrict__ out) {
  const int K = 1024;
  __shared__ short8 lA[2][512];
  __shared__ short8 lB[2][512];
  int tid = threadIdx.x;
  int w = tid >> 6, l = tid & 63, lr = l & 15, lq = l >> 4;
  int gid = blockIdx.x;
  int xcd = gid & 7, j = gid >> 3;     // 64 blocks per XCD
  int yloc = j & 7, xt = j >> 3;       // 8 y x 8 x per XCD
  int m0 = (xcd * 8 + yloc) * 128, n0 = xt * 128;
  int wm = w & 1, wn = w >> 1;
  float4_ acc[4][4] = {};

  const u16* gA0 = A + (size_t)(m0 + w * 32 + lr) * K + lq * 8;
  const u16* gA1 = gA0 + 16 * K;
  const u16* gB0 = Bt + (size_t)(n0 + w * 32 + lr) * K + lq * 8;
  const u16* gB1 = gB0 + 16 * K;

  auto stage = [&](int buf, int k0) {
    async_cp16(gA0 + k0, &lA[buf][(w * 2 + 0) * 64 + l]);
    async_cp16(gA1 + k0, &lA[buf][(w * 2 + 1) * 64 + l]);
    async_cp16(gB0 + k0, &lB[buf][(w * 2 + 0) * 64 + l]);
    async_cp16(gB1 + k0, &lB[buf][(w * 2 + 1) * 64 + l]);
  };
  auto compute = [&](int buf) {
    short8 af[4], bf[4];
#pragma unroll
    for (int t = 0; t < 4; t++) {
      af[t] = lA[buf][(wm * 4 + t) * 64 + l];
      bf[t] = lB[buf][(wn * 4 + t) * 64 + l];
    }
#pragma unroll
    for (int mt = 0; mt < 4; mt++)
#pragma unroll
      for (int nt = 0; nt < 4; nt++)
        acc[mt][nt] = __builtin_amdgcn_mfma_f32_16x16x32_bf16(af[mt], bf[nt], acc[mt][nt], 0, 0, 0);
  };

  stage(0, 0);
  for (int k0 = 0; k0 < K; k0 += 64) {
    __syncthreads();
    stage(1, k0 + 32);
    compute(0);
    __syncthreads();
    if (k0 + 64 < K) stage(0, k0 + 64);
    compute(1);
  }

#pragma unroll
  for (int nt = 0; nt < 4; nt++) {
    int gn = n0 + wn * 64 + nt * 16 + lr;
    float bv = bias[gn];
#pragma unroll
    for (int mt = 0; mt < 4; mt++)
#pragma unroll
      for (int r = 0; r < 4; r++) {
        int gm = m0 + wm * 64 + mt * 16 + lq * 4 + r;
        out[(size_t)gm * 1024 + gn] = acc[mt][nt][r] + bv;
      }
  }
}

// ---------------- flash attention: swapped QK^T, in-register P ----------------
// Block = 4 waves = 128 q rows (32/wave), KV-step 64, double-buffered. Grid 1024.
// S = mfma(A=K_frag, B=Q_frag): output lane (lq,lr) holds S[kv][q=lr] with
// kv = sub*32 + pi(lq*4+r). K rows are PERMUTED at staging:
//   pi0(i) = 8*(i>>2) + (i&3)        (S0: f=0,1 -> kv 8*lq + r)
//   pi1(i) = 8*((i>>2)^2) + 4 + (i&3) (S1: f=2,3 -> kv 8*(lq^2)+4+r)
// so after exp+pack, lane's own w0,w1 = PV A-frag words kv 8lq..+3 and the
// partner's y0,y1 (kv 8lq+4..+7) arrive via shfl_xor(32). No LDS roundtrip.
// launch_bounds(256,4): request 4 waves/SIMD (4 blocks/CU) — R14 ran at 23%
// occupancy and is stall-bound; LDS (32.8KB) permits 4 blocks.

__global__ __launch_bounds__(256, 4) void attn_kernel(
    const u16* __restrict__ Qb, const u16* __restrict__ Kb,
    const u16* __restrict__ Vt, u16* __restrict__ Ob) {
  const int S = 2048, D = 64;
  __shared__ short8 lK[2][512];            // 16 KB
  __shared__ short8 lV[2][512];            // 16 KB
  int tid = threadIdx.x;
  int w = tid >> 6, l = tid & 63, lr = l & 15, lq = l >> 4;
  int gid = blockIdx.x;
  int xcd = gid & 7, j = gid >> 3;        // j in [0,128)
  int bh = xcd * 8 + (j >> 4);            // qblk-major: consecutive j share bh
  int qblk = j & 15;                      // 0..15
  int q0 = qblk * 128 + w * 32;
  const u16* Qh = Qb + (size_t)bh * S * D;
  const u16* Kh = Kb + (size_t)bh * S * D;
  const u16* Vh = Vt + (size_t)bh * D * S;

  short8 qf[2][2];
#pragma unroll
  for (int qg = 0; qg < 2; qg++) {
    qf[qg][0] = *(const short8*)(Qh + (q0 + qg * 16 + lr) * D + lq * 8);
    qf[qg][1] = *(const short8*)(Qh + (q0 + qg * 16 + lr) * D + 32 + lq * 8);
  }

  float ls[2] = {};
  float4_ o[2][4] = {};

  // K staging sources: chunk c = w*2+i; sub = w>>1; f = (w&1)*2+i.
  // lane supplies K[kv0 + sub*32 + pi_f(lr)][(f&1)*32 + lq*8 ..+8]
  const u16* kgsrc[2];
#pragma unroll
  for (int i = 0; i < 2; i++) {
    int f = (w & 1) * 2 + i;
    int sub = w >> 1;
    int kvl = sub * 32 + ((f < 2) ? (8 * (lr >> 2) + (lr & 3))
                                  : (8 * ((lr >> 2) ^ 2) + 4 + (lr & 3)));
    kgsrc[i] = Kh + (size_t)kvl * D + (f & 1) * 32 + lq * 8;
  }
  const u16* vg = Vh + (size_t)(w * 16 + lr) * S + lq * 8;

  auto stage = [&](int buf, int kv0) {
    async_cp16(kgsrc[0] + (size_t)kv0 * D, &lK[buf][(w * 2 + 0) * 64 + l]);
    async_cp16(kgsrc[1] + (size_t)kv0 * D, &lK[buf][(w * 2 + 1) * 64 + l]);
    async_cp16(vg + kv0, &lV[buf][(w * 2 + 0) * 64 + l]);
    async_cp16(vg + kv0 + 32, &lV[buf][(w * 2 + 1) * 64 + l]);
  };

  auto compute = [&](int buf) {
#pragma unroll
    for (int sub = 0; sub < 2; sub++) {
      short8 kf0 = lK[buf][(sub * 4 + 0) * 64 + l];   // pi0 rows, d 0..31
      short8 kf1 = lK[buf][(sub * 4 + 1) * 64 + l];   // pi0 rows, d 32..63
      short8 kf2 = lK[buf][(sub * 4 + 2) * 64 + l];   // pi1 rows, d 0..31
      short8 kf3 = lK[buf][(sub * 4 + 3) * 64 + l];   // pi1 rows, d 32..63
#pragma unroll
      for (int qg = 0; qg < 2; qg++) {
        float4_ z = {0.f, 0.f, 0.f, 0.f};
        float4_ s0 = __builtin_amdgcn_mfma_f32_16x16x32_bf16(kf0, qf[qg][0], z, 0, 0, 0);
        s0 = __builtin_amdgcn_mfma_f32_16x16x32_bf16(kf1, qf[qg][1], s0, 0, 0, 0);
        float4_ s1 = __builtin_amdgcn_mfma_f32_16x16x32_bf16(kf2, qf[qg][0], z, 0, 0, 0);
        s1 = __builtin_amdgcn_mfma_f32_16x16x32_bf16(kf3, qf[qg][1], s1, 0, 0, 0);
        float p00 = fexp2(s0[0]), p01 = fexp2(s0[1]);
        float p02 = fexp2(s0[2]), p03 = fexp2(s0[3]);
        float p10 = fexp2(s1[0]), p11 = fexp2(s1[1]);
        float p12 = fexp2(s1[2]), p13 = fexp2(s1[3]);
        u32 w0 = pk_trunc(p00, p01), w1 = pk_trunc(p02, p03);
        u32 y0 = pk_trunc(p10, p11), y1 = pk_trunc(p12, p13);
        float a = ls[qg];
        a = accum_pk(w0, a); a = accum_pk(w1, a);
        a = accum_pk(y0, a); a = accum_pk(y1, a);
        ls[qg] = a;
        u32 W2 = (u32)__shfl_xor((int)y0, 32, 64);   // kv 8lq+4,+5 (from lq^2)
        u32 W3 = (u32)__shfl_xor((int)y1, 32, 64);   // kv 8lq+6,+7
        u32x4 pw = {w0, w1, W2, W3};
        short8 pa = __builtin_bit_cast(short8, pw);  // A-frag: P[q=lr][kv=8lq..+7]
#pragma unroll
        for (int dt = 0; dt < 4; dt++)
          o[qg][dt] = __builtin_amdgcn_mfma_f32_16x16x32_bf16(
              pa, lV[buf][(dt * 2 + sub) * 64 + l], o[qg][dt], 0, 0, 0);
      }
    }
  };

  stage(0, 0);
  for (int kv0 = 0; kv0 < S; kv0 += 128) {
    __syncthreads();
    stage(1, kv0 + 64);
    compute(0);
    __syncthreads();
    if (kv0 + 128 < S) stage(0, kv0 + 128);
    compute(1);
  }

  int b = bh >> 4, h = bh & 15;
#pragma unroll
  for (int qg = 0; qg < 2; qg++) {
    float s = ls[qg];
    s += __shfl_xor(s, 16, 64);
    s += __shfl_xor(s, 32, 64);   // full denom for q = q0+qg*16+lr, all lanes of column lr
    float inv[4];
#pragma unroll
    for (int r = 0; r < 4; r++)
      inv[r] = 1.0f / __shfl(s, lq * 4 + r, 64);   // denom for q-row lq*4+r
#pragma unroll
    for (int dt = 0; dt < 4; dt++)
#pragma unroll
      for (int r = 0; r < 4; r++) {
        int s_ = q0 + qg * 16 + lq * 4 + r;
        Ob[((size_t)(b * 2048 + s_)) * 1024 + h * 64 + dt * 16 + lr] =
            f2b(o[qg][dt][r] * inv[r]);
      }
  }
}

// ---------------- launch ----------------

extern "C" void kernel_launch(void* const* d_in, const int* in_sizes, int n_in,
                              void* d_out, int out_size, void* d_ws, size_t ws_size,
                              hipStream_t stream) {
  const float* x     = (const float*)d_in[0];   // [4,2048,1024]
  const float* w_qkv = (const float*)d_in[1];   // [1024,3072]
  const float* w_out = (const float*)d_in[2];   // [1024,1024]
  const float* b_out = (const float*)d_in[3];   // [1024]
  float* out = (float*)d_out;

  char* ws = (char*)d_ws;
  u16* Xb  = (u16*)(ws);                    // 16 MB (x bf16; reused as O)
  u16* Wqt = (u16*)(ws + (16u << 20));      // 6 MB  (w_qkv^T bf16)
  u16* Wot = (u16*)(ws + (22u << 20));      // 2 MB  (w_out^T bf16)
  u16* QKV = (u16*)(ws + (24u << 20));      // 48 MB: Q | K | (V region unused)
  u16* Qb  = QKV;
  u16* Kb  = QKV + 8388608;
  u16* Vt  = (u16*)(ws + (72u << 20));      // 16 MB [b,h,d,s] (written by gemm_qkv)
  u16* Ob  = Xb;                            // O overwrites Xb

  prepass_kernel<<<12288, 256, 0, stream>>>(x, Xb, w_qkv, Wqt, w_out, Wot);
  gemm_qkv_kernel<<<1536, 256, 0, stream>>>(Xb, Wqt, QKV, Vt);
  attn_kernel<<<1024, 256, 0, stream>>>(Qb, Kb, Vt, Ob);
  gemm_out_kernel<<<512, 256, 0, stream>>>(Ob, Wot, b_out, out);
}